// Round 3
// baseline (389.422 us; speedup 1.0000x reference)
//
#include <hip/hip_runtime.h>

typedef unsigned short u16;
typedef unsigned int   u32;
typedef float f32x4 __attribute__((ext_vector_type(4)));
typedef short s16x8 __attribute__((ext_vector_type(8)));

#define NB    65536
#define K1    512
#define N1    1152
#define G1D   384
#define K2    384
#define G2D   16
#define NL    256

__device__ inline u16 f2bf(float f) {
  u32 u = __float_as_uint(f);
  u += 0x7fffu + ((u >> 16) & 1u);
  return (u16)(u >> 16);
}
__device__ inline float bf2f(u16 h) { return __uint_as_float(((u32)h) << 16); }
__device__ inline float sigmoidf_(float x) { return 1.0f / (1.0f + __expf(-x)); }
__device__ inline float tanhf_(float x) {
  float e = __expf(2.0f * fabsf(x));
  float t = 1.0f - 2.0f / (e + 1.0f);
  return copysignf(t, x);
}

// ---- prep: W1 [512][1152] f32 -> FRAGMENT-MAJOR bf16 (blocks 0..143) and
//      W2 [384][48] -> [48][384] bf16 (blocks 144..191), fused into one kernel.
// W1t layout: frag(g, ut, kt) is 1KB: 64 lanes x 16B. lane = (u&15) + quad*16
// holds B[ut*16 + (u&15)][kt*32 + quad*8 + e], e=0..7.
__global__ __launch_bounds__(256) void prep_w(const float* __restrict__ w1k,
                                              u16* __restrict__ W1t,
                                              const float* __restrict__ w2k,
                                              u16* __restrict__ W2t) {
  __shared__ float tile[64][65];
  const int id = blockIdx.x;
  if (id < 144) {
    const int nt = (id % 18) * 64;   // 18 n-tiles (384/64=6 per gate: no straddle)
    const int ktb = (id / 18) * 64;  // 8 k-tiles
    const int tr = threadIdx.x >> 4;
    const int tc = (threadIdx.x & 15) * 4;
#pragma unroll
    for (int p = 0; p < 4; p++) {
      int k = ktb + p * 16 + tr;
      float4 v = *(const float4*)(w1k + (long)k * N1 + nt + tc);
      tile[p * 16 + tr][tc + 0] = v.x;
      tile[p * 16 + tr][tc + 1] = v.y;
      tile[p * 16 + tr][tc + 2] = v.z;
      tile[p * 16 + tr][tc + 3] = v.w;
    }
    __syncthreads();
    const int nl = threadIdx.x >> 3;        // 0..31
    const int kc = (threadIdx.x & 7) * 8;   // 8 consecutive k, same quad
#pragma unroll
    for (int p = 0; p < 2; p++) {
      int n = nl + p * 32;
      int c = nt + n;                 // global column 0..1151
      int g = c / 384;
      int urem = c - g * 384;
      int ut = urem >> 4, u16c = urem & 15;
      int k0 = ktb + kc;
      int kt = k0 >> 5, qd = (k0 >> 3) & 3;
      union { uint4 v; u16 u[8]; } o;
#pragma unroll
      for (int j = 0; j < 8; j++) o.u[j] = f2bf(tile[kc + j][n]);
      long off = ((long)((g * 24 + ut) * 16 + kt) * 64 + qd * 16 + u16c) * 8;
      *(uint4*)(W1t + off) = o.v;
    }
  } else {
    const int n = id - 144;           // 0..47
    if (threadIdx.x < 48) {
      const int k0 = threadIdx.x * 8;
      union { uint4 v; u16 u[8]; } o;
#pragma unroll
      for (int j = 0; j < 8; j++) o.u[j] = f2bf(w2k[(k0 + j) * 48 + n]);
      *(uint4*)(W2t + n * K2 + k0) = o.v;
    }
  }
}

// ---- FUSED concat-cast + GEMM1 + gates: H1 = gru1_gates([x1|x2] @ W1^T) ----
// v4: prep_a fused away. A staged f32->bf16 in registers (T14 split: loads for
// step t+3 issued at t, packed+ds_written at t+1, consumed at t+3 -> one full
// step of HBM latency cover). B direct global->reg from fragment-major W1t.
// NEW: af(t+1) LDS fragments prefetched during step t's MFMA (depth-4 buffer
// already holds them), so MFMA never waits ds_read latency.
// One raw s_barrier per k-step; lgkmcnt(0) drains ds_writes before it; vmem
// waits left to compiler auto-waitcnt (fine-grained, never forced to 0 here).
__global__ __launch_bounds__(256, 2) void gemm1gate(const float* __restrict__ x1,
                                                    const float* __restrict__ x2,
                                                    const u16* __restrict__ Bf,
                                                    const float* __restrict__ bias,
                                                    u16* __restrict__ H1) {
  __shared__ u16 As[4][128 * 32];   // 32 KB, 4-deep
  const int tid = threadIdx.x;
  const int wave = tid >> 6, lane = tid & 63;
  const int quad = lane >> 4, l16 = lane & 15;

  // XCD swizzle: 64 m-stripes per XCD, 12 consecutive u-blocks per stripe.
  const int id = blockIdx.x;
  const int xcd = id & 7;
  const int s = id >> 3;           // 0..767
  const int sd = s / 12;           // 0..63
  const int ublk = s - sd * 12;    // 0..11
  const int mbase = (xcd * 64 + sd) * 128;
  const int ucbase = ublk * 32;

  const int wm = (wave & 1) * 64;
  const int wuidx = wave >> 1;                 // 0..1
  const int ut0 = ublk * 2 + wuidx;            // u-tile (16-wide) 0..23

  f32x4 acc[3][4];
#pragma unroll
  for (int g = 0; g < 3; g++)
#pragma unroll
    for (int i = 0; i < 4; i++)
#pragma unroll
      for (int r = 0; r < 4; r++) acc[g][i][r] = 0.0f;

  // A staging: thread -> rows r0, r0+64; k-chunk pre-swizzled by (r0>>1)&3.
  // k-window t*32..t*32+32: t<12 entirely x1 (cols 0..383), t>=12 entirely x2.
  const int r0 = tid >> 2;
  const int kcg = ((tid & 3) ^ ((r0 >> 1) & 3)) * 8;
  const float* x1a = x1 + (long)(mbase + r0) * 384 + kcg;
  const float* x1b = x1 + (long)(mbase + 64 + r0) * 384 + kcg;
  const float* x2a = x2 + ((long)(mbase + r0) * 128 + kcg - 384);
  const float* x2b = x2 + ((long)(mbase + 64 + r0) * 128 + kcg - 384);
  const u16* Bl = Bf + lane * 8;   // per-lane 16B within each 1KB fragment

#define LOADA(T, R) do {                                                     \
    const float* pa_ = ((T) < 12) ? (x1a + (T) * 32) : (x2a + (T) * 32);     \
    const float* pb_ = ((T) < 12) ? (x1b + (T) * 32) : (x2b + (T) * 32);     \
    R[0] = ((const float4*)pa_)[0]; R[1] = ((const float4*)pa_)[1];          \
    R[2] = ((const float4*)pb_)[0]; R[3] = ((const float4*)pb_)[1];          \
  } while (0)

#define PACKWRITE(BUFI, R) do {                                              \
    union { uint4 v; u16 u[8]; } oa_, ob_;                                   \
    const float* fa_ = (const float*)&R[0];                                  \
    const float* fb_ = (const float*)&R[2];                                  \
    _Pragma("unroll")                                                        \
    for (int j_ = 0; j_ < 8; j_++) {                                         \
      oa_.u[j_] = f2bf(fa_[j_]); ob_.u[j_] = f2bf(fb_[j_]);                  \
    }                                                                        \
    *(uint4*)(&As[BUFI][tid * 8]) = oa_.v;                                   \
    *(uint4*)(&As[BUFI][2048 + tid * 8]) = ob_.v;                            \
  } while (0)

#define BLOAD(T, DST) do {                                                   \
    _Pragma("unroll")                                                        \
    for (int g_ = 0; g_ < 3; g_++)                                           \
      DST[g_] = *(const s16x8*)(Bl + (long)((g_ * 24 + ut0) * 16 + (T)) * 512); \
  } while (0)

  // A fragment read offsets within one LDS buffer
  int aoff[4];
#pragma unroll
  for (int i = 0; i < 4; i++) {
    int ra = wm + i * 16 + l16;
    aoff[i] = ra * 32 + ((quad ^ ((ra >> 1) & 3)) << 3);
  }

  // prologue: A(0),A(1) -> LDS buf0/buf1; B(0) -> regs; A(2) in flight; af(0) prefetch
  float4 rp0[4], rp1[4], rc[4], rn[4];
  LOADA(0, rp0);
  LOADA(1, rp1);
  s16x8 bn[3];
  BLOAD(0, bn);
  LOADA(2, rc);
  PACKWRITE(0, rp0);
  PACKWRITE(1, rp1);
  asm volatile("s_waitcnt lgkmcnt(0)" ::: "memory");
  __builtin_amdgcn_s_barrier();
  s16x8 afn[4];
#pragma unroll
  for (int i = 0; i < 4; i++) afn[i] = *(const s16x8*)(&As[0][0] + aoff[i]);

#pragma unroll
  for (int t = 0; t < 16; ++t) {
    s16x8 bcur[3], afc[4];
#pragma unroll
    for (int g = 0; g < 3; g++) bcur[g] = bn[g];
#pragma unroll
    for (int i = 0; i < 4; i++) afc[i] = afn[i];
    if (t < 15) BLOAD(t + 1, bn);       // B for next step
    if (t < 13) LOADA(t + 3, rn);       // A f32 loads, 3 steps ahead
    if (t < 14) PACKWRITE((t + 2) & 3, rc);  // publish A(t+2) (loaded at t-1)
    asm volatile("s_waitcnt lgkmcnt(0)" ::: "memory");  // ds_writes visible
    __builtin_amdgcn_s_barrier();
    if (t < 15) {                       // prefetch next step's A fragments
      const u16* nb = &As[(t + 1) & 3][0];
#pragma unroll
      for (int i = 0; i < 4; i++) afn[i] = *(const s16x8*)(nb + aoff[i]);
    }
    __builtin_amdgcn_s_setprio(1);
#pragma unroll
    for (int g = 0; g < 3; g++)
#pragma unroll
      for (int mi = 0; mi < 4; mi++)
        acc[g][mi] = __builtin_amdgcn_mfma_f32_16x16x32_bf16(afc[mi], bcur[g], acc[g][mi], 0, 0, 0);
    __builtin_amdgcn_s_setprio(0);
    if (t < 13) {
#pragma unroll
      for (int i = 0; i < 4; i++) rc[i] = rn[i];
    }
  }
#undef LOADA
#undef PACKWRITE
#undef BLOAD

  // epilogue: gates
  {
    int u = ucbase + wuidx * 16 + l16;
    float bz = bias[u] + bias[1152 + u];
    float br = bias[384 + u] + bias[1536 + u];
    float bh0 = bias[768 + u];
    float bh1 = bias[1920 + u];
#pragma unroll
    for (int mi = 0; mi < 4; mi++) {
#pragma unroll
      for (int rr = 0; rr < 4; rr++) {
        int row = mbase + wm + mi * 16 + quad * 4 + rr;
        float z  = sigmoidf_(acc[0][mi][rr] + bz);
        float rg = sigmoidf_(acc[1][mi][rr] + br);
        float hc = tanhf_(acc[2][mi][rr] + bh0 + rg * bh1);
        H1[(long)row * G1D + u] = f2bf((1.0f - z) * hc);
      }
    }
  }
}

// ---- FUSED GEMM2 + gates + FC + softmax ----
__global__ __launch_bounds__(256) void gemm2fc(const u16* __restrict__ H1b,
                                               const u16* __restrict__ W2t,
                                               const float* __restrict__ bias2,
                                               const float* __restrict__ w1,
                                               const float* __restrict__ fb1,
                                               const float* __restrict__ w2,
                                               const float* __restrict__ fb2,
                                               const float* __restrict__ g1,
                                               const float* __restrict__ g2,
                                               float* __restrict__ out) {
  __shared__ u16 As[128 * 32];      // 8 KB
  __shared__ u16 Bs[48 * 32];       // 3 KB
  __shared__ float h2s[128 * 17];   // 8.5 KB
  const int tid = threadIdx.x;
  const int wave = tid >> 6, lane = tid & 63;
  const int quad = lane >> 4, l16 = lane & 15;
  const int mbase = blockIdx.x * 128;

  f32x4 acc[2][3];
#pragma unroll
  for (int i = 0; i < 2; i++)
#pragma unroll
    for (int j = 0; j < 3; j++)
#pragma unroll
      for (int r = 0; r < 4; r++) acc[i][j][r] = 0.0f;

  const int r0 = tid >> 2, kc = (tid & 3) * 8;
  const u16* Aptr = H1b + (long)(mbase + r0) * K2 + kc;

  for (int k0 = 0; k0 < K2; k0 += 32) {
    uint4 a0 = *(const uint4*)(Aptr + k0);
    uint4 a1 = *(const uint4*)(Aptr + 64 * K2 + k0);
    uint4 bv;
    if (tid < 192) bv = *(const uint4*)(W2t + r0 * K2 + k0 + kc);
    __syncthreads();
    *(uint4*)(&As[r0 * 32 + kc]) = a0;
    *(uint4*)(&As[(64 + r0) * 32 + kc]) = a1;
    if (tid < 192) *(uint4*)(&Bs[r0 * 32 + kc]) = bv;
    __syncthreads();
    s16x8 af[2], bfr[3];
#pragma unroll
    for (int mi = 0; mi < 2; mi++)
      af[mi] = *(const s16x8*)(&As[(wave * 32 + mi * 16 + l16) * 32 + quad * 8]);
#pragma unroll
    for (int ni = 0; ni < 3; ni++)
      bfr[ni] = *(const s16x8*)(&Bs[(ni * 16 + l16) * 32 + quad * 8]);
#pragma unroll
    for (int mi = 0; mi < 2; mi++)
#pragma unroll
      for (int ni = 0; ni < 3; ni++)
        acc[mi][ni] = __builtin_amdgcn_mfma_f32_16x16x32_bf16(af[mi], bfr[ni], acc[mi][ni], 0, 0, 0);
  }

  {
    const int u = l16;
    const float b0z = bias2[u],      b1z = bias2[48 + u];
    const float b0r = bias2[16 + u], b1r = bias2[64 + u];
    const float b0h = bias2[32 + u], b1h = bias2[80 + u];
#pragma unroll
    for (int mi = 0; mi < 2; mi++) {
#pragma unroll
      for (int rr = 0; rr < 4; rr++) {
        int row_l = wave * 32 + mi * 16 + quad * 4 + rr;
        float z  = sigmoidf_(acc[mi][0][rr] + b0z + b1z);
        float rg = sigmoidf_(acc[mi][1][rr] + b0r + b1r);
        float hc = tanhf_(acc[mi][2][rr] + b0h + rg * b1h);
        h2s[row_l * 17 + u] = (1.0f - z) * hc;
      }
    }
  }
  __syncthreads();

  // Phase 2: fc + softmax, wave-per-row (32 rows per wave)
#pragma unroll 1
  for (int r = 0; r < 32; r++) {
    int row_l = wave * 32 + r;
    float h[16];
#pragma unroll
    for (int uu = 0; uu < 16; uu++) h[uu] = h2s[row_l * 17 + uu];
    float e[4];
    float mx = -1e30f;
#pragma unroll
    for (int i = 0; i < 4; i++) {
      int c = i * 64 + lane;
      float a1 = fb1[c], a2 = fb2[c];
#pragma unroll
      for (int uu = 0; uu < 16; uu++) {
        a1 = fmaf(h[uu], w1[uu * 256 + c], a1);
        a2 = fmaf(h[uu], w2[uu * 256 + c], a2);
      }
      float d = g1[c] * tanhf_(a1) + g2[c] * tanhf_(a2);
      e[i] = d;
      mx = fmaxf(mx, d);
    }
#pragma unroll
    for (int off = 32; off >= 1; off >>= 1) mx = fmaxf(mx, __shfl_xor(mx, off, 64));
    float sum = 0.0f;
#pragma unroll
    for (int i = 0; i < 4; i++) { e[i] = __expf(e[i] - mx); sum += e[i]; }
#pragma unroll
    for (int off = 32; off >= 1; off >>= 1) sum += __shfl_xor(sum, off, 64);
    float inv = 1.0f / sum;
    float* orow = out + (long)(mbase + row_l) * NL;
#pragma unroll
    for (int i = 0; i < 4; i++) orow[i * 64 + lane] = e[i] * inv;
  }
}

extern "C" void kernel_launch(void* const* d_in, const int* in_sizes, int n_in,
                              void* d_out, int out_size, void* d_ws, size_t ws_size,
                              hipStream_t stream) {
  const float* x1   = (const float*)d_in[0];
  const float* x2   = (const float*)d_in[1];
  const float* w1k  = (const float*)d_in[2];   // gru1_kernel (512 x 1152)
  const float* b1g  = (const float*)d_in[4];   // gru1_bias (2 x 1152)
  const float* w2k  = (const float*)d_in[5];   // gru2_kernel (384 x 48)
  const float* b2g  = (const float*)d_in[7];   // gru2_bias (2 x 48)
  const float* fcw1 = (const float*)d_in[8];
  const float* fcb1 = (const float*)d_in[9];
  const float* fcw2 = (const float*)d_in[10];
  const float* fcb2 = (const float*)d_in[11];
  const float* fcg1 = (const float*)d_in[12];
  const float* fcg2 = (const float*)d_in[13];
  float* out = (float*)d_out;

  char* ws = (char*)d_ws;
  u16* W1t = (u16*)(ws + 0);            // 1152*512*2  = 1179648 (fragment-major)
  u16* H1  = (u16*)(ws + 1179648);      // 65536*384*2 = 50331648
  u16* W2t = (u16*)(ws + 51511296);     // 48*384*2    = 36864

  hipLaunchKernelGGL(prep_w, dim3(192), dim3(256), 0, stream, w1k, W1t, w2k, W2t);
  hipLaunchKernelGGL(gemm1gate, dim3(6144), dim3(256), 0, stream, x1, x2, W1t, b1g, H1);
  hipLaunchKernelGGL(gemm2fc, dim3(512), dim3(256), 0, stream, H1, W2t, b2g,
                     fcw1, fcb1, fcw2, fcb2, fcg1, fcg2, out);
}

// Round 4
// 371.805 us; speedup vs baseline: 1.0474x; 1.0474x over previous
//
#include <hip/hip_runtime.h>

typedef unsigned short u16;
typedef unsigned int   u32;
typedef float f32x4  __attribute__((ext_vector_type(4)));
typedef float f32x16 __attribute__((ext_vector_type(16)));
typedef short s16x8  __attribute__((ext_vector_type(8)));

#define NB    65536
#define K1    512
#define N1    1152
#define G1D   384
#define K2    384
#define G2D   16
#define NL    256

__device__ inline u16 f2bf(float f) {
  u32 u = __float_as_uint(f);
  u += 0x7fffu + ((u >> 16) & 1u);
  return (u16)(u >> 16);
}
__device__ inline float bf2f(u16 h) { return __uint_as_float(((u32)h) << 16); }
__device__ inline float sigmoidf_(float x) { return 1.0f / (1.0f + __expf(-x)); }
__device__ inline float tanhf_(float x) {
  float e = __expf(2.0f * fabsf(x));
  float t = 1.0f - 2.0f / (e + 1.0f);
  return copysignf(t, x);
}

// async global->LDS, 16B per lane; LDS dest must be wave-uniform base + lane*16
__device__ inline void gld16(const u16* g, u16* l) {
  __builtin_amdgcn_global_load_lds(
      (const __attribute__((address_space(1))) void*)g,
      (__attribute__((address_space(3))) void*)l, 16, 0, 0);
}

// ---- prep: concat x1|x2 -> bf16 A (NB x 512) ----
__global__ void prep_a(const float* __restrict__ x1, const float* __restrict__ x2,
                       u16* __restrict__ Abf) {
  int t = blockIdx.x * 256 + threadIdx.x;   // 8 elems/thread
  int i = t * 8;
  int row = i >> 9, col = i & 511;
  const float* src = (col < 384) ? (x1 + row * 384 + col) : (x2 + row * 128 + (col - 384));
  float4 v0 = ((const float4*)src)[0];
  float4 v1 = ((const float4*)src)[1];
  union { uint4 v; u16 u[8]; } o;
  o.u[0] = f2bf(v0.x); o.u[1] = f2bf(v0.y); o.u[2] = f2bf(v0.z); o.u[3] = f2bf(v0.w);
  o.u[4] = f2bf(v1.x); o.u[5] = f2bf(v1.y); o.u[6] = f2bf(v1.z); o.u[7] = f2bf(v1.w);
  *(uint4*)(Abf + i) = o.v;
}

// ---- prep: W1 [512][1152] f32 -> 32x32x16-FRAGMENT-MAJOR bf16 (blocks 0..143)
//      and W2 [384][48] -> [48][384] bf16 (blocks 144..191).
// W1t layout: frag(g, u32t, k16t) is 1KB: 64 lanes x 16B.
// lane l = khal*32 + nl holds B[n = u32t*32 + nl][k = k16t*16 + khal*8 + e].
// u16 offset = (((g*12 + u32t)*32 + k16t)*64 + khal*32 + nl)*8 + e.
__global__ __launch_bounds__(256) void prep_w(const float* __restrict__ w1k,
                                              u16* __restrict__ W1t,
                                              const float* __restrict__ w2k,
                                              u16* __restrict__ W2t) {
  __shared__ float tile[64][65];
  const int id = blockIdx.x;
  if (id < 144) {
    const int nt = (id % 18) * 64;   // 18 n-tiles (384 = 6*64: no gate straddle)
    const int ktb = (id / 18) * 64;  // 8 k-tiles
    const int tr = threadIdx.x >> 4;
    const int tc = (threadIdx.x & 15) * 4;
#pragma unroll
    for (int p = 0; p < 4; p++) {
      int k = ktb + p * 16 + tr;
      float4 v = *(const float4*)(w1k + (long)k * N1 + nt + tc);
      tile[p * 16 + tr][tc + 0] = v.x;
      tile[p * 16 + tr][tc + 1] = v.y;
      tile[p * 16 + tr][tc + 2] = v.z;
      tile[p * 16 + tr][tc + 3] = v.w;
    }
    __syncthreads();
    const int nl = threadIdx.x >> 3;        // 0..31
    const int kc = (threadIdx.x & 7) * 8;   // 8 consecutive k (same khal group)
#pragma unroll
    for (int p = 0; p < 2; p++) {
      int n = nl + p * 32;
      int c = nt + n;                 // global column 0..1151
      int g = c / 384;
      int un = c - g * 384;
      int u32t = un >> 5, nl32 = un & 31;
      int k0 = ktb + kc;
      int k16t = k0 >> 4, khal = (k0 >> 3) & 1;
      union { uint4 v; u16 u[8]; } o;
#pragma unroll
      for (int j = 0; j < 8; j++) o.u[j] = f2bf(tile[kc + j][n]);
      long off = ((long)((g * 12 + u32t) * 32 + k16t) * 64 + khal * 32 + nl32) * 8;
      *(uint4*)(W1t + off) = o.v;
    }
  } else {
    const int n = id - 144;           // 0..47
    if (threadIdx.x < 48) {
      const int k0 = threadIdx.x * 8;
      union { uint4 v; u16 u[8]; } o;
#pragma unroll
      for (int j = 0; j < 8; j++) o.u[j] = f2bf(w2k[(k0 + j) * 48 + n]);
      *(uint4*)(W2t + n * K2 + k0) = o.v;
    }
  }
}

// ---- FUSED GEMM1 + gates: H1 = gru1_gates(A @ W1^T), 32x32x16 MFMA ----
// v5: R2's proven pipeline skeleton (4-deep LDS A, gld16 2 ahead, B direct
// global->reg 1 ahead, single raw barrier + counted vmcnt, setprio) with the
// MFMA shape swapped to 32x32x16_bf16: 2x FLOP/inst, same inst count/step.
// Wave tile 64m x 32u x 3 gates; block 128m x (64u x 3g); grid 3072.
__global__ __launch_bounds__(256, 2) void gemm1gate(const u16* __restrict__ A,
                                                    const u16* __restrict__ Bf,
                                                    const float* __restrict__ bias,
                                                    u16* __restrict__ H1) {
  __shared__ u16 As[4][128 * 32];   // 32 KB, 4-deep
  const int tid = threadIdx.x;
  const int wave = tid >> 6, lane = tid & 63;
  const int half = lane >> 5;       // k-half selector (32x32 frag)
  const int l32 = lane & 31;

  // XCD swizzle: 64 m-stripes per XCD, 6 consecutive u-blocks per stripe.
  const int id = blockIdx.x;
  const int xcd = id & 7;
  const int s = id >> 3;           // 0..383
  const int sd = s / 6;            // 0..63
  const int ublk = s - sd * 6;     // 0..5
  const int mbase = (xcd * 64 + sd) * 128;

  const int wm = (wave & 1) * 64;
  const int wu = (wave >> 1);                  // 0/1: u32-half of the 64u block
  const int u32t = ublk * 2 + wu;              // 0..11 (per gate)

  f32x16 acc[3][2];
#pragma unroll
  for (int g = 0; g < 3; g++)
#pragma unroll
    for (int mf = 0; mf < 2; mf++)
#pragma unroll
      for (int r = 0; r < 16; r++) acc[g][mf][r] = 0.0f;

  // A staging: thread -> rows r0, r0+64; k-chunk pre-swizzled by (r0>>1)&3
  const int r0 = tid >> 2;
  const int kcg = ((tid & 3) ^ ((r0 >> 1) & 3)) * 8;
  const u16* Aptr  = A + (long)(mbase + r0) * K1 + kcg;
  const u16* Aptr2 = Aptr + 64 * K1;
  const u16* Bl = Bf + lane * 8;   // per-lane 16B within each 1KB fragment
  u16* ldsA0 = &As[0][0];          // buffer bases, tid*8 within

  // A fragment read offsets: frag (mf, kh): row = wm+mf*32+l32,
  // logical chunk = kh*2+half, phys = chunk ^ ((row>>1)&3)
  int aoff[2][2];
#pragma unroll
  for (int mf = 0; mf < 2; mf++)
#pragma unroll
    for (int kh = 0; kh < 2; kh++) {
      int row = wm + mf * 32 + l32;
      int ch = (kh * 2 + half) ^ ((row >> 1) & 3);
      aoff[mf][kh] = row * 32 + ch * 8;
    }

#define BLOAD(T, DST) do {                                                      \
    _Pragma("unroll")                                                           \
    for (int g_ = 0; g_ < 3; g_++)                                              \
      _Pragma("unroll")                                                         \
      for (int kh_ = 0; kh_ < 2; kh_++)                                         \
        DST[g_][kh_] = *(const s16x8*)(Bl +                                     \
            (long)(((g_ * 12 + u32t) * 32) + (T) * 2 + kh_) * 512);             \
  } while (0)

  // prologue: B(0) -> regs; stage A(0), A(1) into buffers 0,1
  s16x8 bn[3][2];
  BLOAD(0, bn);
  asm volatile("" ::: "memory");
  gld16(Aptr,       &As[0][tid * 8]);
  gld16(Aptr2,      &As[0][2048 + tid * 8]);
  gld16(Aptr + 32,  &As[1][tid * 8]);
  gld16(Aptr2 + 32, &As[1][2048 + tid * 8]);

#pragma unroll
  for (int t = 0; t < 16; ++t) {
    s16x8 bcur[3][2];
#pragma unroll
    for (int g = 0; g < 3; g++)
#pragma unroll
      for (int kh = 0; kh < 2; kh++) bcur[g][kh] = bn[g][kh];

    if (t < 15) BLOAD(t + 1, bn);       // B for next step
    asm volatile("" ::: "memory");
    if (t < 14) {                        // stage A (k-step t+2), 2 ahead
      const int ta = t + 2;
      gld16(Aptr  + ta * 32, &As[(t + 2) & 3][tid * 8]);
      gld16(Aptr2 + ta * 32, &As[(t + 2) & 3][2048 + tid * 8]);
    }
    // counted wait: retire A(t),B(t); steady outstanding after issue:
    // A(t+1)2 + B(t+1)6 + A(t+2)2 = 10
    if (t < 14)       asm volatile("s_waitcnt vmcnt(10)" ::: "memory");
    else if (t == 14) asm volatile("s_waitcnt vmcnt(8)"  ::: "memory");
    else              asm volatile("s_waitcnt vmcnt(0)"  ::: "memory");
    __builtin_amdgcn_s_barrier();
    asm volatile("" ::: "memory");

    const u16* buf = &As[t & 3][0];
    s16x8 af[2][2];
#pragma unroll
    for (int mf = 0; mf < 2; mf++)
#pragma unroll
      for (int kh = 0; kh < 2; kh++)
        af[mf][kh] = *(const s16x8*)(buf + aoff[mf][kh]);

    __builtin_amdgcn_s_setprio(1);
#pragma unroll
    for (int g = 0; g < 3; g++)
#pragma unroll
      for (int mf = 0; mf < 2; mf++) {
        acc[g][mf] = __builtin_amdgcn_mfma_f32_32x32x16_bf16(af[mf][0], bcur[g][0], acc[g][mf], 0, 0, 0);
        acc[g][mf] = __builtin_amdgcn_mfma_f32_32x32x16_bf16(af[mf][1], bcur[g][1], acc[g][mf], 0, 0, 0);
      }
    __builtin_amdgcn_s_setprio(0);
  }
#undef BLOAD

  // epilogue: gates. C/D 32x32 map: col=lane&31, row=(reg&3)+8*(reg>>2)+4*half
  {
    int u = ublk * 64 + wu * 32 + l32;
    float bz = bias[u] + bias[1152 + u];
    float br = bias[384 + u] + bias[1536 + u];
    float bh0 = bias[768 + u];
    float bh1 = bias[1920 + u];
#pragma unroll
    for (int mf = 0; mf < 2; mf++) {
#pragma unroll
      for (int r = 0; r < 16; r++) {
        int rl = (r & 3) + 8 * (r >> 2) + 4 * half;
        int row = mbase + wm + mf * 32 + rl;
        float z  = sigmoidf_(acc[0][mf][r] + bz);
        float rg = sigmoidf_(acc[1][mf][r] + br);
        float hc = tanhf_(acc[2][mf][r] + bh0 + rg * bh1);
        H1[(long)row * G1D + u] = f2bf((1.0f - z) * hc);
      }
    }
  }
}

// ---- FUSED GEMM2 + gates + FC + softmax ----
__global__ __launch_bounds__(256) void gemm2fc(const u16* __restrict__ H1b,
                                               const u16* __restrict__ W2t,
                                               const float* __restrict__ bias2,
                                               const float* __restrict__ w1,
                                               const float* __restrict__ fb1,
                                               const float* __restrict__ w2,
                                               const float* __restrict__ fb2,
                                               const float* __restrict__ g1,
                                               const float* __restrict__ g2,
                                               float* __restrict__ out) {
  __shared__ u16 As[128 * 32];      // 8 KB
  __shared__ u16 Bs[48 * 32];       // 3 KB
  __shared__ float h2s[128 * 17];   // 8.5 KB
  const int tid = threadIdx.x;
  const int wave = tid >> 6, lane = tid & 63;
  const int quad = lane >> 4, l16 = lane & 15;
  const int mbase = blockIdx.x * 128;

  f32x4 acc[2][3];
#pragma unroll
  for (int i = 0; i < 2; i++)
#pragma unroll
    for (int j = 0; j < 3; j++)
#pragma unroll
      for (int r = 0; r < 4; r++) acc[i][j][r] = 0.0f;

  const int r0 = tid >> 2, kc = (tid & 3) * 8;
  const u16* Aptr = H1b + (long)(mbase + r0) * K2 + kc;

  for (int k0 = 0; k0 < K2; k0 += 32) {
    uint4 a0 = *(const uint4*)(Aptr + k0);
    uint4 a1 = *(const uint4*)(Aptr + 64 * K2 + k0);
    uint4 bv;
    if (tid < 192) bv = *(const uint4*)(W2t + r0 * K2 + k0 + kc);
    __syncthreads();
    *(uint4*)(&As[r0 * 32 + kc]) = a0;
    *(uint4*)(&As[(64 + r0) * 32 + kc]) = a1;
    if (tid < 192) *(uint4*)(&Bs[r0 * 32 + kc]) = bv;
    __syncthreads();
    s16x8 af[2], bfr[3];
#pragma unroll
    for (int mi = 0; mi < 2; mi++)
      af[mi] = *(const s16x8*)(&As[(wave * 32 + mi * 16 + l16) * 32 + quad * 8]);
#pragma unroll
    for (int ni = 0; ni < 3; ni++)
      bfr[ni] = *(const s16x8*)(&Bs[(ni * 16 + l16) * 32 + quad * 8]);
#pragma unroll
    for (int mi = 0; mi < 2; mi++)
#pragma unroll
      for (int ni = 0; ni < 3; ni++)
        acc[mi][ni] = __builtin_amdgcn_mfma_f32_16x16x32_bf16(af[mi], bfr[ni], acc[mi][ni], 0, 0, 0);
  }

  {
    const int u = l16;
    const float b0z = bias2[u],      b1z = bias2[48 + u];
    const float b0r = bias2[16 + u], b1r = bias2[64 + u];
    const float b0h = bias2[32 + u], b1h = bias2[80 + u];
#pragma unroll
    for (int mi = 0; mi < 2; mi++) {
#pragma unroll
      for (int rr = 0; rr < 4; rr++) {
        int row_l = wave * 32 + mi * 16 + quad * 4 + rr;
        float z  = sigmoidf_(acc[mi][0][rr] + b0z + b1z);
        float rg = sigmoidf_(acc[mi][1][rr] + b0r + b1r);
        float hc = tanhf_(acc[mi][2][rr] + b0h + rg * b1h);
        h2s[row_l * 17 + u] = (1.0f - z) * hc;
      }
    }
  }
  __syncthreads();

  // Phase 2: fc + softmax, wave-per-row (32 rows per wave)
#pragma unroll 1
  for (int r = 0; r < 32; r++) {
    int row_l = wave * 32 + r;
    float h[16];
#pragma unroll
    for (int uu = 0; uu < 16; uu++) h[uu] = h2s[row_l * 17 + uu];
    float e[4];
    float mx = -1e30f;
#pragma unroll
    for (int i = 0; i < 4; i++) {
      int c = i * 64 + lane;
      float a1 = fb1[c], a2 = fb2[c];
#pragma unroll
      for (int uu = 0; uu < 16; uu++) {
        a1 = fmaf(h[uu], w1[uu * 256 + c], a1);
        a2 = fmaf(h[uu], w2[uu * 256 + c], a2);
      }
      float d = g1[c] * tanhf_(a1) + g2[c] * tanhf_(a2);
      e[i] = d;
      mx = fmaxf(mx, d);
    }
#pragma unroll
    for (int off = 32; off >= 1; off >>= 1) mx = fmaxf(mx, __shfl_xor(mx, off, 64));
    float sum = 0.0f;
#pragma unroll
    for (int i = 0; i < 4; i++) { e[i] = __expf(e[i] - mx); sum += e[i]; }
#pragma unroll
    for (int off = 32; off >= 1; off >>= 1) sum += __shfl_xor(sum, off, 64);
    float inv = 1.0f / sum;
    float* orow = out + (long)(mbase + row_l) * NL;
#pragma unroll
    for (int i = 0; i < 4; i++) orow[i * 64 + lane] = e[i] * inv;
  }
}

extern "C" void kernel_launch(void* const* d_in, const int* in_sizes, int n_in,
                              void* d_out, int out_size, void* d_ws, size_t ws_size,
                              hipStream_t stream) {
  const float* x1   = (const float*)d_in[0];
  const float* x2   = (const float*)d_in[1];
  const float* w1k  = (const float*)d_in[2];   // gru1_kernel (512 x 1152)
  const float* b1g  = (const float*)d_in[4];   // gru1_bias (2 x 1152)
  const float* w2k  = (const float*)d_in[5];   // gru2_kernel (384 x 48)
  const float* b2g  = (const float*)d_in[7];   // gru2_bias (2 x 48)
  const float* fcw1 = (const float*)d_in[8];
  const float* fcb1 = (const float*)d_in[9];
  const float* fcw2 = (const float*)d_in[10];
  const float* fcb2 = (const float*)d_in[11];
  const float* fcg1 = (const float*)d_in[12];
  const float* fcg2 = (const float*)d_in[13];
  float* out = (float*)d_out;

  char* ws = (char*)d_ws;
  u16* Abf = (u16*)(ws + 0);            // 65536*512*2   = 67108864
  u16* W1t = (u16*)(ws + 67108864);     // 1152*512*2    = 1179648 (32x32 frag-major)
  u16* H1  = (u16*)(ws + 68288512);     // 65536*384*2   = 50331648
  u16* W2t = (u16*)(ws + 118620160);    // 48*384*2      = 36864

  hipLaunchKernelGGL(prep_a, dim3(16384), dim3(256), 0, stream, x1, x2, Abf);
  hipLaunchKernelGGL(prep_w, dim3(192), dim3(256), 0, stream, w1k, W1t, w2k, W2t);
  hipLaunchKernelGGL(gemm1gate, dim3(3072), dim3(256), 0, stream, Abf, W1t, b1g, H1);
  hipLaunchKernelGGL(gemm2fc, dim3(512), dim3(256), 0, stream, H1, W2t, b2g,
                     fcw1, fcb1, fcw2, fcb2, fcg1, fcg2, out);
}

// Round 5
// 369.781 us; speedup vs baseline: 1.0531x; 1.0055x over previous
//
#include <hip/hip_runtime.h>

typedef unsigned short u16;
typedef unsigned int   u32;
typedef float f32x4 __attribute__((ext_vector_type(4)));
typedef short s16x8 __attribute__((ext_vector_type(8)));

#define NB    65536
#define K1    512
#define N1    1152
#define G1D   384
#define K2    384
#define G2D   16
#define NL    256

__device__ inline u16 f2bf(float f) {
  u32 u = __float_as_uint(f);
  u += 0x7fffu + ((u >> 16) & 1u);
  return (u16)(u >> 16);
}
__device__ inline float bf2f(u16 h) { return __uint_as_float(((u32)h) << 16); }
__device__ inline float sigmoidf_(float x) { return 1.0f / (1.0f + __expf(-x)); }
__device__ inline float tanhf_(float x) {
  float e = __expf(2.0f * fabsf(x));
  float t = 1.0f - 2.0f / (e + 1.0f);
  return copysignf(t, x);
}

// async global->LDS, 16B per lane; LDS dest must be wave-uniform base + lane*16
__device__ inline void gld16(const u16* g, u16* l) {
  __builtin_amdgcn_global_load_lds(
      (const __attribute__((address_space(1))) void*)g,
      (__attribute__((address_space(3))) void*)l, 16, 0, 0);
}

// ---- prep: concat x1|x2 -> bf16 A (NB x 512) ----
__global__ void prep_a(const float* __restrict__ x1, const float* __restrict__ x2,
                       u16* __restrict__ Abf) {
  int t = blockIdx.x * 256 + threadIdx.x;   // 8 elems/thread
  int i = t * 8;
  int row = i >> 9, col = i & 511;
  const float* src = (col < 384) ? (x1 + row * 384 + col) : (x2 + row * 128 + (col - 384));
  float4 v0 = ((const float4*)src)[0];
  float4 v1 = ((const float4*)src)[1];
  union { uint4 v; u16 u[8]; } o;
  o.u[0] = f2bf(v0.x); o.u[1] = f2bf(v0.y); o.u[2] = f2bf(v0.z); o.u[3] = f2bf(v0.w);
  o.u[4] = f2bf(v1.x); o.u[5] = f2bf(v1.y); o.u[6] = f2bf(v1.z); o.u[7] = f2bf(v1.w);
  *(uint4*)(Abf + i) = o.v;
}

// ---- prep: W1 [512][1152] f32 -> 16x16x32 FRAGMENT-MAJOR bf16 (blocks 0..143)
//      and W2 [384][48] -> [48][384] bf16 (blocks 144..191).
// W1t layout: frag(g, ut, kt) is 1KB: 64 lanes x 16B. lane = (u&15) + quad*16
// holds B[ut*16 + (u&15)][kt*32 + quad*8 + e], e=0..7.
// u16 offset = (((g*24+ut)*16 + kt)*64 + quad*16 + (u&15)) * 8 + e.
__global__ __launch_bounds__(256) void prep_w(const float* __restrict__ w1k,
                                              u16* __restrict__ W1t,
                                              const float* __restrict__ w2k,
                                              u16* __restrict__ W2t) {
  __shared__ float tile[64][65];
  const int id = blockIdx.x;
  if (id < 144) {
    const int nt = (id % 18) * 64;   // 18 n-tiles (384/64=6 per gate: no straddle)
    const int ktb = (id / 18) * 64;  // 8 k-tiles
    const int tr = threadIdx.x >> 4;
    const int tc = (threadIdx.x & 15) * 4;
#pragma unroll
    for (int p = 0; p < 4; p++) {
      int k = ktb + p * 16 + tr;
      float4 v = *(const float4*)(w1k + (long)k * N1 + nt + tc);
      tile[p * 16 + tr][tc + 0] = v.x;
      tile[p * 16 + tr][tc + 1] = v.y;
      tile[p * 16 + tr][tc + 2] = v.z;
      tile[p * 16 + tr][tc + 3] = v.w;
    }
    __syncthreads();
    const int nl = threadIdx.x >> 3;        // 0..31
    const int kc = (threadIdx.x & 7) * 8;   // 8 consecutive k, same quad
#pragma unroll
    for (int p = 0; p < 2; p++) {
      int n = nl + p * 32;
      int c = nt + n;                 // global column 0..1151
      int g = c / 384;
      int urem = c - g * 384;
      int ut = urem >> 4, u16c = urem & 15;
      int k0 = ktb + kc;
      int kt = k0 >> 5, qd = (k0 >> 3) & 3;
      union { uint4 v; u16 u[8]; } o;
#pragma unroll
      for (int j = 0; j < 8; j++) o.u[j] = f2bf(tile[kc + j][n]);
      long off = ((long)((g * 24 + ut) * 16 + kt) * 64 + qd * 16 + u16c) * 8;
      *(uint4*)(W1t + off) = o.v;
    }
  } else {
    const int n = id - 144;           // 0..47
    if (threadIdx.x < 48) {
      const int k0 = threadIdx.x * 8;
      union { uint4 v; u16 u[8]; } o;
#pragma unroll
      for (int j = 0; j < 8; j++) o.u[j] = f2bf(w2k[(k0 + j) * 48 + n]);
      *(uint4*)(W2t + n * K2 + k0) = o.v;
    }
  }
}

// ---- FUSED GEMM1 + gates: H1 = gru1_gates(A @ W1^T) ----
// v6: R2's verified 16x16 pipeline, block retiled 128m -> 256m to halve L2
// traffic per output (A re-read 12x -> 6x per stripe; B frags shared by all
// 4 waves, L1-served). Wave = 64m quarter x 32u x 3 gates (96 AGPR acc).
// 4-deep LDS A (64KB), gld16 staged 2 steps ahead, B frag-major direct->reg
// 1 step ahead, ONE raw barrier + counted vmcnt per step, setprio on MFMA.
__global__ __launch_bounds__(256, 2) void gemm1gate(const u16* __restrict__ A,
                                                    const u16* __restrict__ Bf,
                                                    const float* __restrict__ bias,
                                                    u16* __restrict__ H1) {
  __shared__ u16 As[4][256 * 32];   // 64 KB, 4-deep, 16KB per k-step
  const int tid = threadIdx.x;
  const int wave = tid >> 6, lane = tid & 63;
  const int quad = lane >> 4, l16 = lane & 15;

  // XCD swizzle: grid 3072 = 8 xcd * 32 stripes * 12 ublk; 12 consecutive
  // u-blocks of one 256-row stripe land on the same XCD (A panel L2-hot).
  const int id = blockIdx.x;
  const int xcd = id & 7;
  const int s = id >> 3;           // 0..383
  const int sd = s / 12;           // 0..31
  const int ublk = s - sd * 12;    // 0..11
  const int mbase = (xcd * 32 + sd) * 256;
  const int ucbase = ublk * 32;
  const int wm = wave * 64;        // wave's m-quarter
  const int ut0 = ublk * 2;        // two 16-wide u-tiles per block

  f32x4 acc[3][4][2];              // 96 AGPR
#pragma unroll
  for (int g = 0; g < 3; g++)
#pragma unroll
    for (int i = 0; i < 4; i++)
#pragma unroll
      for (int j = 0; j < 2; j++)
#pragma unroll
        for (int r = 0; r < 4; r++) acc[g][i][j][r] = 0.0f;

  // A staging: thread -> rows r0 + 64p (p=0..3); k-chunk pre-swizzled by
  // (r0>>1)&3 (same for all p since 64p preserves (row>>1)&3).
  const int r0 = tid >> 2;
  const int kcg = ((tid & 3) ^ ((r0 >> 1) & 3)) * 8;
  const u16* Ap0 = A + (long)(mbase + r0) * K1 + kcg;
  const u16* Ap1 = Ap0 + 64 * K1;
  const u16* Ap2 = Ap0 + 128 * K1;
  const u16* Ap3 = Ap0 + 192 * K1;
  const u16* Bl = Bf + lane * 8;   // per-lane 16B within each 1KB fragment

  // A fragment read offsets within one LDS buffer
  int aoff[4];
#pragma unroll
  for (int i = 0; i < 4; i++) {
    int ra = wm + i * 16 + l16;
    aoff[i] = ra * 32 + ((quad ^ ((ra >> 1) & 3)) << 3);
  }

#define BLOAD(T, DST) do {                                                   \
    _Pragma("unroll")                                                        \
    for (int g_ = 0; g_ < 3; g_++)                                           \
      _Pragma("unroll")                                                      \
      for (int j_ = 0; j_ < 2; j_++)                                         \
        DST[g_][j_] = *(const s16x8*)(Bl +                                   \
            (long)((g_ * 24 + ut0 + j_) * 16 + (T)) * 512);                  \
  } while (0)

#define STAGEA(T, BUFI) do {                                                 \
    gld16(Ap0 + (T) * 32, &As[BUFI][0 * 2048 + tid * 8]);                    \
    gld16(Ap1 + (T) * 32, &As[BUFI][1 * 2048 + tid * 8]);                    \
    gld16(Ap2 + (T) * 32, &As[BUFI][2 * 2048 + tid * 8]);                    \
    gld16(Ap3 + (T) * 32, &As[BUFI][3 * 2048 + tid * 8]);                    \
  } while (0)

  // prologue: B(0) -> regs; stage A(0), A(1) into buffers 0,1
  s16x8 bn[3][2];
  BLOAD(0, bn);
  asm volatile("" ::: "memory");
  STAGEA(0, 0);
  STAGEA(1, 1);

#pragma unroll
  for (int t = 0; t < 16; ++t) {
    s16x8 bcur[3][2];
#pragma unroll
    for (int g = 0; g < 3; g++)
#pragma unroll
      for (int j = 0; j < 2; j++) bcur[g][j] = bn[g][j];

    if (t < 15) BLOAD(t + 1, bn);       // B for next step (6 loads)
    asm volatile("" ::: "memory");
    if (t < 14) STAGEA(t + 2, (t + 2) & 3);  // A 2 steps ahead (4 gld16)
    // counted wait: retire A(t),B(t). Issue order per iter: B 6, A 4.
    // Steady in-flight before wait: [A(t)4? no -- A(t) retired at t-? ]
    // Induction: after wait at iter t-1 -> {A(t+1)4, B(t+1)6? }..
    // Concretely: younger-than-B(t) = A(t+1)4 + B(t+1)6 + A(t+2)4 = 14.
    if (t < 14)       asm volatile("s_waitcnt vmcnt(14)" ::: "memory");
    else if (t == 14) asm volatile("s_waitcnt vmcnt(10)" ::: "memory");  // A(15)+B(15)
    else              asm volatile("s_waitcnt vmcnt(0)"  ::: "memory");
    __builtin_amdgcn_s_barrier();
    asm volatile("" ::: "memory");

    const u16* buf = &As[t & 3][0];
    s16x8 af[4];
#pragma unroll
    for (int i = 0; i < 4; i++) af[i] = *(const s16x8*)(buf + aoff[i]);

    __builtin_amdgcn_s_setprio(1);
#pragma unroll
    for (int g = 0; g < 3; g++) {
#pragma unroll
      for (int mi = 0; mi < 4; mi++) {
        acc[g][mi][0] = __builtin_amdgcn_mfma_f32_16x16x32_bf16(af[mi], bcur[g][0], acc[g][mi][0], 0, 0, 0);
        acc[g][mi][1] = __builtin_amdgcn_mfma_f32_16x16x32_bf16(af[mi], bcur[g][1], acc[g][mi][1], 0, 0, 0);
      }
    }
    __builtin_amdgcn_s_setprio(0);
  }
#undef BLOAD
#undef STAGEA

  // epilogue: gates
#pragma unroll
  for (int j = 0; j < 2; j++) {
    int u = ucbase + j * 16 + l16;
    float bz = bias[u] + bias[1152 + u];
    float br = bias[384 + u] + bias[1536 + u];
    float bh0 = bias[768 + u];
    float bh1 = bias[1920 + u];
#pragma unroll
    for (int mi = 0; mi < 4; mi++) {
#pragma unroll
      for (int rr = 0; rr < 4; rr++) {
        int row = mbase + wm + mi * 16 + quad * 4 + rr;
        float z  = sigmoidf_(acc[0][mi][j][rr] + bz);
        float rg = sigmoidf_(acc[1][mi][j][rr] + br);
        float hc = tanhf_(acc[2][mi][j][rr] + bh0 + rg * bh1);
        H1[(long)row * G1D + u] = f2bf((1.0f - z) * hc);
      }
    }
  }
}

// ---- FUSED GEMM2 + gates + FC + softmax ----
__global__ __launch_bounds__(256) void gemm2fc(const u16* __restrict__ H1b,
                                               const u16* __restrict__ W2t,
                                               const float* __restrict__ bias2,
                                               const float* __restrict__ w1,
                                               const float* __restrict__ fb1,
                                               const float* __restrict__ w2,
                                               const float* __restrict__ fb2,
                                               const float* __restrict__ g1,
                                               const float* __restrict__ g2,
                                               float* __restrict__ out) {
  __shared__ u16 As[128 * 32];      // 8 KB
  __shared__ u16 Bs[48 * 32];       // 3 KB
  __shared__ float h2s[128 * 17];   // 8.5 KB
  const int tid = threadIdx.x;
  const int wave = tid >> 6, lane = tid & 63;
  const int quad = lane >> 4, l16 = lane & 15;
  const int mbase = blockIdx.x * 128;

  f32x4 acc[2][3];
#pragma unroll
  for (int i = 0; i < 2; i++)
#pragma unroll
    for (int j = 0; j < 3; j++)
#pragma unroll
      for (int r = 0; r < 4; r++) acc[i][j][r] = 0.0f;

  const int r0 = tid >> 2, kc = (tid & 3) * 8;
  const u16* Aptr = H1b + (long)(mbase + r0) * K2 + kc;

  for (int k0 = 0; k0 < K2; k0 += 32) {
    uint4 a0 = *(const uint4*)(Aptr + k0);
    uint4 a1 = *(const uint4*)(Aptr + 64 * K2 + k0);
    uint4 bv;
    if (tid < 192) bv = *(const uint4*)(W2t + r0 * K2 + k0 + kc);
    __syncthreads();
    *(uint4*)(&As[r0 * 32 + kc]) = a0;
    *(uint4*)(&As[(64 + r0) * 32 + kc]) = a1;
    if (tid < 192) *(uint4*)(&Bs[r0 * 32 + kc]) = bv;
    __syncthreads();
    s16x8 af[2], bfr[3];
#pragma unroll
    for (int mi = 0; mi < 2; mi++)
      af[mi] = *(const s16x8*)(&As[(wave * 32 + mi * 16 + l16) * 32 + quad * 8]);
#pragma unroll
    for (int ni = 0; ni < 3; ni++)
      bfr[ni] = *(const s16x8*)(&Bs[(ni * 16 + l16) * 32 + quad * 8]);
#pragma unroll
    for (int mi = 0; mi < 2; mi++)
#pragma unroll
      for (int ni = 0; ni < 3; ni++)
        acc[mi][ni] = __builtin_amdgcn_mfma_f32_16x16x32_bf16(af[mi], bfr[ni], acc[mi][ni], 0, 0, 0);
  }

  {
    const int u = l16;
    const float b0z = bias2[u],      b1z = bias2[48 + u];
    const float b0r = bias2[16 + u], b1r = bias2[64 + u];
    const float b0h = bias2[32 + u], b1h = bias2[80 + u];
#pragma unroll
    for (int mi = 0; mi < 2; mi++) {
#pragma unroll
      for (int rr = 0; rr < 4; rr++) {
        int row_l = wave * 32 + mi * 16 + quad * 4 + rr;
        float z  = sigmoidf_(acc[mi][0][rr] + b0z + b1z);
        float rg = sigmoidf_(acc[mi][1][rr] + b0r + b1r);
        float hc = tanhf_(acc[mi][2][rr] + b0h + rg * b1h);
        h2s[row_l * 17 + u] = (1.0f - z) * hc;
      }
    }
  }
  __syncthreads();

  // Phase 2: fc + softmax, wave-per-row (32 rows per wave)
#pragma unroll 1
  for (int r = 0; r < 32; r++) {
    int row_l = wave * 32 + r;
    float h[16];
#pragma unroll
    for (int uu = 0; uu < 16; uu++) h[uu] = h2s[row_l * 17 + uu];
    float e[4];
    float mx = -1e30f;
#pragma unroll
    for (int i = 0; i < 4; i++) {
      int c = i * 64 + lane;
      float a1 = fb1[c], a2 = fb2[c];
#pragma unroll
      for (int uu = 0; uu < 16; uu++) {
        a1 = fmaf(h[uu], w1[uu * 256 + c], a1);
        a2 = fmaf(h[uu], w2[uu * 256 + c], a2);
      }
      float d = g1[c] * tanhf_(a1) + g2[c] * tanhf_(a2);
      e[i] = d;
      mx = fmaxf(mx, d);
    }
#pragma unroll
    for (int off = 32; off >= 1; off >>= 1) mx = fmaxf(mx, __shfl_xor(mx, off, 64));
    float sum = 0.0f;
#pragma unroll
    for (int i = 0; i < 4; i++) { e[i] = __expf(e[i] - mx); sum += e[i]; }
#pragma unroll
    for (int off = 32; off >= 1; off >>= 1) sum += __shfl_xor(sum, off, 64);
    float inv = 1.0f / sum;
    float* orow = out + (long)(mbase + row_l) * NL;
#pragma unroll
    for (int i = 0; i < 4; i++) orow[i * 64 + lane] = e[i] * inv;
  }
}

extern "C" void kernel_launch(void* const* d_in, const int* in_sizes, int n_in,
                              void* d_out, int out_size, void* d_ws, size_t ws_size,
                              hipStream_t stream) {
  const float* x1   = (const float*)d_in[0];
  const float* x2   = (const float*)d_in[1];
  const float* w1k  = (const float*)d_in[2];   // gru1_kernel (512 x 1152)
  const float* b1g  = (const float*)d_in[4];   // gru1_bias (2 x 1152)
  const float* w2k  = (const float*)d_in[5];   // gru2_kernel (384 x 48)
  const float* b2g  = (const float*)d_in[7];   // gru2_bias (2 x 48)
  const float* fcw1 = (const float*)d_in[8];
  const float* fcb1 = (const float*)d_in[9];
  const float* fcw2 = (const float*)d_in[10];
  const float* fcb2 = (const float*)d_in[11];
  const float* fcg1 = (const float*)d_in[12];
  const float* fcg2 = (const float*)d_in[13];
  float* out = (float*)d_out;

  char* ws = (char*)d_ws;
  u16* Abf = (u16*)(ws + 0);            // 65536*512*2   = 67108864
  u16* W1t = (u16*)(ws + 67108864);     // 1152*512*2    = 1179648 (16x16 frag-major)
  u16* H1  = (u16*)(ws + 68288512);     // 65536*384*2   = 50331648
  u16* W2t = (u16*)(ws + 118620160);    // 48*384*2      = 36864

  hipLaunchKernelGGL(prep_a, dim3(16384), dim3(256), 0, stream, x1, x2, Abf);
  hipLaunchKernelGGL(prep_w, dim3(192), dim3(256), 0, stream, w1k, W1t, w2k, W2t);
  hipLaunchKernelGGL(gemm1gate, dim3(3072), dim3(256), 0, stream, Abf, W1t, b1g, H1);
  hipLaunchKernelGGL(gemm2fc, dim3(512), dim3(256), 0, stream, H1, W2t, b2g,
                     fcw1, fcb1, fcw2, fcb2, fcg1, fcg2, out);
}

// Round 6
// 369.509 us; speedup vs baseline: 1.0539x; 1.0007x over previous
//
#include <hip/hip_runtime.h>

typedef unsigned short u16;
typedef unsigned int   u32;
typedef float f32x4 __attribute__((ext_vector_type(4)));
typedef short s16x8 __attribute__((ext_vector_type(8)));

#define NB    65536
#define K1    512
#define N1    1152
#define G1D   384
#define K2    384
#define G2D   16
#define NL    256

__device__ inline u16 f2bf(float f) {
  u32 u = __float_as_uint(f);
  u += 0x7fffu + ((u >> 16) & 1u);
  return (u16)(u >> 16);
}
__device__ inline float bf2f(u16 h) { return __uint_as_float(((u32)h) << 16); }
__device__ inline float sigmoidf_(float x) { return 1.0f / (1.0f + __expf(-x)); }
__device__ inline float tanhf_(float x) {
  float e = __expf(2.0f * fabsf(x));
  float t = 1.0f - 2.0f / (e + 1.0f);
  return copysignf(t, x);
}

// async global->LDS, 16B per lane; LDS dest must be wave-uniform base + lane*16
__device__ inline void gld16(const u16* g, u16* l) {
  __builtin_amdgcn_global_load_lds(
      (const __attribute__((address_space(1))) void*)g,
      (__attribute__((address_space(3))) void*)l, 16, 0, 0);
}

// ---- prep: concat x1|x2 -> bf16 A (NB x 512) ----
__global__ void prep_a(const float* __restrict__ x1, const float* __restrict__ x2,
                       u16* __restrict__ Abf) {
  int t = blockIdx.x * 256 + threadIdx.x;   // 8 elems/thread
  int i = t * 8;
  int row = i >> 9, col = i & 511;
  const float* src = (col < 384) ? (x1 + row * 384 + col) : (x2 + row * 128 + (col - 384));
  float4 v0 = ((const float4*)src)[0];
  float4 v1 = ((const float4*)src)[1];
  union { uint4 v; u16 u[8]; } o;
  o.u[0] = f2bf(v0.x); o.u[1] = f2bf(v0.y); o.u[2] = f2bf(v0.z); o.u[3] = f2bf(v0.w);
  o.u[4] = f2bf(v1.x); o.u[5] = f2bf(v1.y); o.u[6] = f2bf(v1.z); o.u[7] = f2bf(v1.w);
  *(uint4*)(Abf + i) = o.v;
}

// ---- prep: W1 [512][1152] f32 -> 16x16x32 FRAGMENT-MAJOR bf16 (blocks 0..143)
//      and W2 [384][48] -> [48][384] bf16 (blocks 144..191).
// W1t layout: frag(g, ut, kt) is 1KB: 64 lanes x 16B. lane = (u&15) + quad*16
// holds B[ut*16 + (u&15)][kt*32 + quad*8 + e], e=0..7.
// u16 offset = (((g*24+ut)*16 + kt)*64 + quad*16 + (u&15)) * 8 + e.
__global__ __launch_bounds__(256) void prep_w(const float* __restrict__ w1k,
                                              u16* __restrict__ W1t,
                                              const float* __restrict__ w2k,
                                              u16* __restrict__ W2t) {
  __shared__ float tile[64][65];
  const int id = blockIdx.x;
  if (id < 144) {
    const int nt = (id % 18) * 64;   // 18 n-tiles (384/64=6 per gate: no straddle)
    const int ktb = (id / 18) * 64;  // 8 k-tiles
    const int tr = threadIdx.x >> 4;
    const int tc = (threadIdx.x & 15) * 4;
#pragma unroll
    for (int p = 0; p < 4; p++) {
      int k = ktb + p * 16 + tr;
      float4 v = *(const float4*)(w1k + (long)k * N1 + nt + tc);
      tile[p * 16 + tr][tc + 0] = v.x;
      tile[p * 16 + tr][tc + 1] = v.y;
      tile[p * 16 + tr][tc + 2] = v.z;
      tile[p * 16 + tr][tc + 3] = v.w;
    }
    __syncthreads();
    const int nl = threadIdx.x >> 3;        // 0..31
    const int kc = (threadIdx.x & 7) * 8;   // 8 consecutive k, same quad
#pragma unroll
    for (int p = 0; p < 2; p++) {
      int n = nl + p * 32;
      int c = nt + n;                 // global column 0..1151
      int g = c / 384;
      int urem = c - g * 384;
      int ut = urem >> 4, u16c = urem & 15;
      int k0 = ktb + kc;
      int kt = k0 >> 5, qd = (k0 >> 3) & 3;
      union { uint4 v; u16 u[8]; } o;
#pragma unroll
      for (int j = 0; j < 8; j++) o.u[j] = f2bf(tile[kc + j][n]);
      long off = ((long)((g * 24 + ut) * 16 + kt) * 64 + qd * 16 + u16c) * 8;
      *(uint4*)(W1t + off) = o.v;
    }
  } else {
    const int n = id - 144;           // 0..47
    if (threadIdx.x < 48) {
      const int k0 = threadIdx.x * 8;
      union { uint4 v; u16 u[8]; } o;
#pragma unroll
      for (int j = 0; j < 8; j++) o.u[j] = f2bf(w2k[(k0 + j) * 48 + n]);
      *(uint4*)(W2t + n * K2 + k0) = o.v;
    }
  }
}

// ---- FUSED GEMM1 + gates: H1 = gru1_gates(A @ W1^T) ----
// R2-exact (verified 108.6 us, MfmaUtil 33, occupancy 40%, 0 conflicts):
// single-barrier counted-vmcnt pipeline. Wave tile 64m x 16u x 3 gates
// (48 AGPR acc); block 128m x 32u; grid 6144, XCD-swizzled (12 u-blocks
// per stripe share one XCD L2).
__global__ __launch_bounds__(256, 4) void gemm1gate(const u16* __restrict__ A,
                                                    const u16* __restrict__ Bf,
                                                    const float* __restrict__ bias,
                                                    u16* __restrict__ H1) {
  __shared__ u16 As[4][128 * 32];   // 32 KB, 4-deep
  const int tid = threadIdx.x;
  const int wave = tid >> 6, lane = tid & 63;
  const int quad = lane >> 4, l16 = lane & 15;

  // XCD swizzle: 64 m-stripes per XCD, 12 consecutive u-blocks per stripe.
  const int id = blockIdx.x;
  const int xcd = id & 7;
  const int s = id >> 3;           // 0..767
  const int sd = s / 12;           // 0..63
  const int ublk = s - sd * 12;    // 0..11
  const int mbase = (xcd * 64 + sd) * 128;
  const int ucbase = ublk * 32;

  const int wm = (wave & 1) * 64;
  const int wuidx = wave >> 1;                 // 0..1
  const int ut0 = ublk * 2 + wuidx;            // u-tile (16-wide) 0..23

  f32x4 acc[3][4];
#pragma unroll
  for (int g = 0; g < 3; g++)
#pragma unroll
    for (int i = 0; i < 4; i++)
#pragma unroll
      for (int r = 0; r < 4; r++) acc[g][i][r] = 0.0f;

  // A staging: thread -> row r0=tid>>2, k-chunk swizzled by (r0>>1)&3
  const int r0 = tid >> 2;
  const int kcg = ((tid & 3) ^ ((r0 >> 1) & 3)) * 8;
  const u16* Aptr  = A + (long)(mbase + r0) * K1 + kcg;
  const u16* Aptr2 = Aptr + 64 * K1;
  const u16* Bl = Bf + lane * 8;   // per-lane 16B within each 1KB fragment

  // A fragment read offsets within one LDS buffer
  int aoff[4];
#pragma unroll
  for (int i = 0; i < 4; i++) {
    int ra = wm + i * 16 + l16;
    aoff[i] = ra * 32 + ((quad ^ ((ra >> 1) & 3)) << 3);
  }

  // prologue: B(0) -> regs, then stage A(0), A(1) into buffers 0,1
  s16x8 bn[3];
#pragma unroll
  for (int g = 0; g < 3; g++)
    bn[g] = *(const s16x8*)(Bl + (long)((g * 24 + ut0) * 16 + 0) * 512);
  asm volatile("" ::: "memory");
  gld16(Aptr,       &As[0][tid * 8]);
  gld16(Aptr2,      &As[0][2048 + tid * 8]);
  gld16(Aptr + 32,  &As[1][tid * 8]);
  gld16(Aptr2 + 32, &As[1][2048 + tid * 8]);

#pragma unroll
  for (int t = 0; t < 16; ++t) {
    // current B = what we prefetched last iter
    s16x8 bcur[3];
#pragma unroll
    for (int g = 0; g < 3; g++) bcur[g] = bn[g];

    // prefetch next B (k-step t+1)
    if (t < 15) {
      const int tb = t + 1;
#pragma unroll
      for (int g = 0; g < 3; g++)
        bn[g] = *(const s16x8*)(Bl + (long)((g * 24 + ut0) * 16 + tb) * 512);
    }
    asm volatile("" ::: "memory");
    // stage A (k-step t+2), 2 ahead
    if (t < 14) {
      const int ta = t + 2;
      gld16(Aptr  + ta * 32, &As[(t + 2) & 3][tid * 8]);
      gld16(Aptr2 + ta * 32, &As[(t + 2) & 3][2048 + tid * 8]);
    }
    // counted wait: retire A(t) and B(t); leave newer prefetches in flight.
    // steady state outstanding after issue: A(t+1)2 B(t+1)3 A(t+2)2 = 7
    if (t < 14)       asm volatile("s_waitcnt vmcnt(7)" ::: "memory");
    else if (t == 14) asm volatile("s_waitcnt vmcnt(5)" ::: "memory");
    else              asm volatile("s_waitcnt vmcnt(0)" ::: "memory");
    __builtin_amdgcn_s_barrier();
    asm volatile("" ::: "memory");

    const u16* buf = &As[t & 3][0];
    s16x8 af[4];
#pragma unroll
    for (int i = 0; i < 4; i++) af[i] = *(const s16x8*)(buf + aoff[i]);

    __builtin_amdgcn_s_setprio(1);
#pragma unroll
    for (int g = 0; g < 3; g++) {
#pragma unroll
      for (int mi = 0; mi < 4; mi++) {
        acc[g][mi] = __builtin_amdgcn_mfma_f32_16x16x32_bf16(af[mi], bcur[g], acc[g][mi], 0, 0, 0);
      }
    }
    __builtin_amdgcn_s_setprio(0);
  }

  // epilogue: gates
  {
    int u = ucbase + wuidx * 16 + l16;
    float bz = bias[u] + bias[1152 + u];
    float br = bias[384 + u] + bias[1536 + u];
    float bh0 = bias[768 + u];
    float bh1 = bias[1920 + u];
#pragma unroll
    for (int mi = 0; mi < 4; mi++) {
#pragma unroll
      for (int rr = 0; rr < 4; rr++) {
        int row = mbase + wm + mi * 16 + quad * 4 + rr;
        float z  = sigmoidf_(acc[0][mi][rr] + bz);
        float rg = sigmoidf_(acc[1][mi][rr] + br);
        float hc = tanhf_(acc[2][mi][rr] + bh0 + rg * bh1);
        H1[(long)row * G1D + u] = f2bf((1.0f - z) * hc);
      }
    }
  }
}

// ---- FUSED GEMM2 + gates + FC + softmax ----
// v2 phase 2: FC weights hoisted into REGISTERS once per block (was: 4096
// global loads per lane re-issued every row). All weight arrays statically
// indexed (fully unrolled). h2s relaid [128][16] so per-row h loads are 4x
// broadcast ds_read_b128. ~184 VGPR @ 2 waves/SIMD -- phase 2 is latency/
// compute bound, not occupancy bound.
__global__ __launch_bounds__(256, 2) void gemm2fc(const u16* __restrict__ H1b,
                                               const u16* __restrict__ W2t,
                                               const float* __restrict__ bias2,
                                               const float* __restrict__ w1,
                                               const float* __restrict__ fb1,
                                               const float* __restrict__ w2,
                                               const float* __restrict__ fb2,
                                               const float* __restrict__ g1,
                                               const float* __restrict__ g2,
                                               float* __restrict__ out) {
  __shared__ u16 As[128 * 32];      // 8 KB
  __shared__ u16 Bs[48 * 32];       // 3 KB
  __shared__ float h2s[128 * 16];   // 8 KB
  const int tid = threadIdx.x;
  const int wave = tid >> 6, lane = tid & 63;
  const int quad = lane >> 4, l16 = lane & 15;
  const int mbase = blockIdx.x * 128;

  f32x4 acc[2][3];
#pragma unroll
  for (int i = 0; i < 2; i++)
#pragma unroll
    for (int j = 0; j < 3; j++)
#pragma unroll
      for (int r = 0; r < 4; r++) acc[i][j][r] = 0.0f;

  const int r0 = tid >> 2, kc = (tid & 3) * 8;
  const u16* Aptr = H1b + (long)(mbase + r0) * K2 + kc;

  for (int k0 = 0; k0 < K2; k0 += 32) {
    uint4 a0 = *(const uint4*)(Aptr + k0);
    uint4 a1 = *(const uint4*)(Aptr + 64 * K2 + k0);
    uint4 bv;
    if (tid < 192) bv = *(const uint4*)(W2t + r0 * K2 + k0 + kc);
    __syncthreads();
    *(uint4*)(&As[r0 * 32 + kc]) = a0;
    *(uint4*)(&As[(64 + r0) * 32 + kc]) = a1;
    if (tid < 192) *(uint4*)(&Bs[r0 * 32 + kc]) = bv;
    __syncthreads();
    s16x8 af[2], bfr[3];
#pragma unroll
    for (int mi = 0; mi < 2; mi++)
      af[mi] = *(const s16x8*)(&As[(wave * 32 + mi * 16 + l16) * 32 + quad * 8]);
#pragma unroll
    for (int ni = 0; ni < 3; ni++)
      bfr[ni] = *(const s16x8*)(&Bs[(ni * 16 + l16) * 32 + quad * 8]);
#pragma unroll
    for (int mi = 0; mi < 2; mi++)
#pragma unroll
      for (int ni = 0; ni < 3; ni++)
        acc[mi][ni] = __builtin_amdgcn_mfma_f32_16x16x32_bf16(af[mi], bfr[ni], acc[mi][ni], 0, 0, 0);
  }

  {
    const int u = l16;
    const float b0z = bias2[u],      b1z = bias2[48 + u];
    const float b0r = bias2[16 + u], b1r = bias2[64 + u];
    const float b0h = bias2[32 + u], b1h = bias2[80 + u];
#pragma unroll
    for (int mi = 0; mi < 2; mi++) {
#pragma unroll
      for (int rr = 0; rr < 4; rr++) {
        int row_l = wave * 32 + mi * 16 + quad * 4 + rr;
        float z  = sigmoidf_(acc[mi][0][rr] + b0z + b1z);
        float rg = sigmoidf_(acc[mi][1][rr] + b0r + b1r);
        float hc = tanhf_(acc[mi][2][rr] + b0h + rg * b1h);
        h2s[row_l * 16 + u] = (1.0f - z) * hc;
      }
    }
  }

  // hoist FC weights into registers (loop-invariant across all 32 rows).
  // statically indexed via fully-unrolled loops -> stays in VGPRs (rule #20).
  float w1r[4][16], w2r[4][16], fb1r[4], fb2r[4], g1r[4], g2r[4];
#pragma unroll
  for (int i = 0; i < 4; i++) {
    int c = i * 64 + lane;
    fb1r[i] = fb1[c]; fb2r[i] = fb2[c]; g1r[i] = g1[c]; g2r[i] = g2[c];
#pragma unroll
    for (int uu = 0; uu < 16; uu++) {
      w1r[i][uu] = w1[uu * 256 + c];
      w2r[i][uu] = w2[uu * 256 + c];
    }
  }
  __syncthreads();

  // Phase 2: fc + softmax, wave-per-row (32 rows per wave)
#pragma unroll 1
  for (int r = 0; r < 32; r++) {
    int row_l = wave * 32 + r;
    // broadcast b128 loads of the row's h2 (all lanes same addr)
    float4 hv0 = *(const float4*)(&h2s[row_l * 16 + 0]);
    float4 hv1 = *(const float4*)(&h2s[row_l * 16 + 4]);
    float4 hv2 = *(const float4*)(&h2s[row_l * 16 + 8]);
    float4 hv3 = *(const float4*)(&h2s[row_l * 16 + 12]);
    float h[16];
    h[0] = hv0.x; h[1] = hv0.y; h[2] = hv0.z; h[3] = hv0.w;
    h[4] = hv1.x; h[5] = hv1.y; h[6] = hv1.z; h[7] = hv1.w;
    h[8] = hv2.x; h[9] = hv2.y; h[10] = hv2.z; h[11] = hv2.w;
    h[12] = hv3.x; h[13] = hv3.y; h[14] = hv3.z; h[15] = hv3.w;
    float e[4];
    float mx = -1e30f;
#pragma unroll
    for (int i = 0; i < 4; i++) {
      float a1 = fb1r[i], a2 = fb2r[i];
#pragma unroll
      for (int uu = 0; uu < 16; uu++) {
        a1 = fmaf(h[uu], w1r[i][uu], a1);
        a2 = fmaf(h[uu], w2r[i][uu], a2);
      }
      float d = g1r[i] * tanhf_(a1) + g2r[i] * tanhf_(a2);
      e[i] = d;
      mx = fmaxf(mx, d);
    }
#pragma unroll
    for (int off = 32; off >= 1; off >>= 1) mx = fmaxf(mx, __shfl_xor(mx, off, 64));
    float sum = 0.0f;
#pragma unroll
    for (int i = 0; i < 4; i++) { e[i] = __expf(e[i] - mx); sum += e[i]; }
#pragma unroll
    for (int off = 32; off >= 1; off >>= 1) sum += __shfl_xor(sum, off, 64);
    float inv = 1.0f / sum;
    float* orow = out + (long)(mbase + row_l) * NL;
#pragma unroll
    for (int i = 0; i < 4; i++) orow[i * 64 + lane] = e[i] * inv;
  }
}

extern "C" void kernel_launch(void* const* d_in, const int* in_sizes, int n_in,
                              void* d_out, int out_size, void* d_ws, size_t ws_size,
                              hipStream_t stream) {
  const float* x1   = (const float*)d_in[0];
  const float* x2   = (const float*)d_in[1];
  const float* w1k  = (const float*)d_in[2];   // gru1_kernel (512 x 1152)
  const float* b1g  = (const float*)d_in[4];   // gru1_bias (2 x 1152)
  const float* w2k  = (const float*)d_in[5];   // gru2_kernel (384 x 48)
  const float* b2g  = (const float*)d_in[7];   // gru2_bias (2 x 48)
  const float* fcw1 = (const float*)d_in[8];
  const float* fcb1 = (const float*)d_in[9];
  const float* fcw2 = (const float*)d_in[10];
  const float* fcb2 = (const float*)d_in[11];
  const float* fcg1 = (const float*)d_in[12];
  const float* fcg2 = (const float*)d_in[13];
  float* out = (float*)d_out;

  char* ws = (char*)d_ws;
  u16* Abf = (u16*)(ws + 0);            // 65536*512*2   = 67108864
  u16* W1t = (u16*)(ws + 67108864);     // 1152*512*2    = 1179648 (16x16 frag-major)
  u16* H1  = (u16*)(ws + 68288512);     // 65536*384*2   = 50331648
  u16* W2t = (u16*)(ws + 118620160);    // 48*384*2      = 36864

  hipLaunchKernelGGL(prep_a, dim3(16384), dim3(256), 0, stream, x1, x2, Abf);
  hipLaunchKernelGGL(prep_w, dim3(192), dim3(256), 0, stream, w1k, W1t, w2k, W2t);
  hipLaunchKernelGGL(gemm1gate, dim3(6144), dim3(256), 0, stream, Abf, W1t, b1g, H1);
  hipLaunchKernelGGL(gemm2fc, dim3(512), dim3(256), 0, stream, H1, W2t, b2g,
                     fcw1, fcb1, fcw2, fcb2, fcg1, fcg2, out);
}

// Round 7
// 364.933 us; speedup vs baseline: 1.0671x; 1.0125x over previous
//
#include <hip/hip_runtime.h>

typedef unsigned short u16;
typedef unsigned int   u32;
typedef float f32x4 __attribute__((ext_vector_type(4)));
typedef short s16x8 __attribute__((ext_vector_type(8)));

#define NB    65536
#define K1    512
#define N1    1152
#define G1D   384
#define K2    384
#define G2D   16
#define NL    256

__device__ inline u16 f2bf(float f) {
  u32 u = __float_as_uint(f);
  u += 0x7fffu + ((u >> 16) & 1u);
  return (u16)(u >> 16);
}
__device__ inline float bf2f(u16 h) { return __uint_as_float(((u32)h) << 16); }
__device__ inline float sigmoidf_(float x) { return 1.0f / (1.0f + __expf(-x)); }
__device__ inline float tanhf_(float x) {
  float e = __expf(2.0f * fabsf(x));
  float t = 1.0f - 2.0f / (e + 1.0f);
  return copysignf(t, x);
}

// async global->LDS, 16B per lane; LDS dest must be wave-uniform base + lane*16
__device__ inline void gld16(const u16* g, u16* l) {
  __builtin_amdgcn_global_load_lds(
      (const __attribute__((address_space(1))) void*)g,
      (__attribute__((address_space(3))) void*)l, 16, 0, 0);
}

// ---- prep (single kernel): blocks 0..16383: concat x1|x2 -> bf16 A (NB x 512)
//      blocks 16384..16527: W1 [512][1152] f32 -> 16x16x32 frag-major bf16
//      blocks 16528..16575: W2 [384][48] -> [48][384] bf16
// W1t layout: frag(g, ut, kt) is 1KB: 64 lanes x 16B. lane = (u&15) + quad*16
// holds B[ut*16 + (u&15)][kt*32 + quad*8 + e], e=0..7.
// u16 offset = (((g*24+ut)*16 + kt)*64 + quad*16 + (u&15)) * 8 + e.
__global__ __launch_bounds__(256) void prep_all(const float* __restrict__ x1,
                                                const float* __restrict__ x2,
                                                u16* __restrict__ Abf,
                                                const float* __restrict__ w1k,
                                                u16* __restrict__ W1t,
                                                const float* __restrict__ w2k,
                                                u16* __restrict__ W2t) {
  __shared__ float tile[64][65];
  const int bid = blockIdx.x;
  if (bid < 16384) {
    // ---- prep_a ----
    int t = bid * 256 + threadIdx.x;   // 8 elems/thread
    int i = t * 8;
    int row = i >> 9, col = i & 511;
    const float* src = (col < 384) ? (x1 + row * 384 + col) : (x2 + row * 128 + (col - 384));
    float4 v0 = ((const float4*)src)[0];
    float4 v1 = ((const float4*)src)[1];
    union { uint4 v; u16 u[8]; } o;
    o.u[0] = f2bf(v0.x); o.u[1] = f2bf(v0.y); o.u[2] = f2bf(v0.z); o.u[3] = f2bf(v0.w);
    o.u[4] = f2bf(v1.x); o.u[5] = f2bf(v1.y); o.u[6] = f2bf(v1.z); o.u[7] = f2bf(v1.w);
    *(uint4*)(Abf + i) = o.v;
    return;
  }
  const int id = bid - 16384;
  if (id < 144) {
    const int nt = (id % 18) * 64;   // 18 n-tiles (384/64=6 per gate: no straddle)
    const int ktb = (id / 18) * 64;  // 8 k-tiles
    const int tr = threadIdx.x >> 4;
    const int tc = (threadIdx.x & 15) * 4;
#pragma unroll
    for (int p = 0; p < 4; p++) {
      int k = ktb + p * 16 + tr;
      float4 v = *(const float4*)(w1k + (long)k * N1 + nt + tc);
      tile[p * 16 + tr][tc + 0] = v.x;
      tile[p * 16 + tr][tc + 1] = v.y;
      tile[p * 16 + tr][tc + 2] = v.z;
      tile[p * 16 + tr][tc + 3] = v.w;
    }
    __syncthreads();
    const int nl = threadIdx.x >> 3;        // 0..31
    const int kc = (threadIdx.x & 7) * 8;   // 8 consecutive k, same quad
#pragma unroll
    for (int p = 0; p < 2; p++) {
      int n = nl + p * 32;
      int c = nt + n;                 // global column 0..1151
      int g = c / 384;
      int urem = c - g * 384;
      int ut = urem >> 4, u16c = urem & 15;
      int k0 = ktb + kc;
      int kt = k0 >> 5, qd = (k0 >> 3) & 3;
      union { uint4 v; u16 u[8]; } o;
#pragma unroll
      for (int j = 0; j < 8; j++) o.u[j] = f2bf(tile[kc + j][n]);
      long off = ((long)((g * 24 + ut) * 16 + kt) * 64 + qd * 16 + u16c) * 8;
      *(uint4*)(W1t + off) = o.v;
    }
  } else {
    const int n = id - 144;           // 0..47
    if (threadIdx.x < 48) {
      const int k0 = threadIdx.x * 8;
      union { uint4 v; u16 u[8]; } o;
#pragma unroll
      for (int j = 0; j < 8; j++) o.u[j] = f2bf(w2k[(k0 + j) * 48 + n]);
      *(uint4*)(W2t + n * K2 + k0) = o.v;
    }
  }
}

// ---- FUSED GEMM1 + gates: H1 = gru1_gates(A @ W1^T) ----
// R2/R6-exact (verified 109 us, MfmaUtil 33, occupancy 40%, 0 conflicts):
// single-barrier counted-vmcnt pipeline. Wave tile 64m x 16u x 3 gates
// (48 AGPR acc); block 128m x 32u; grid 6144, XCD-swizzled (12 u-blocks
// per stripe share one XCD L2).
__global__ __launch_bounds__(256, 4) void gemm1gate(const u16* __restrict__ A,
                                                    const u16* __restrict__ Bf,
                                                    const float* __restrict__ bias,
                                                    u16* __restrict__ H1) {
  __shared__ u16 As[4][128 * 32];   // 32 KB, 4-deep
  const int tid = threadIdx.x;
  const int wave = tid >> 6, lane = tid & 63;
  const int quad = lane >> 4, l16 = lane & 15;

  // XCD swizzle: 64 m-stripes per XCD, 12 consecutive u-blocks per stripe.
  const int id = blockIdx.x;
  const int xcd = id & 7;
  const int s = id >> 3;           // 0..767
  const int sd = s / 12;           // 0..63
  const int ublk = s - sd * 12;    // 0..11
  const int mbase = (xcd * 64 + sd) * 128;
  const int ucbase = ublk * 32;

  const int wm = (wave & 1) * 64;
  const int wuidx = wave >> 1;                 // 0..1
  const int ut0 = ublk * 2 + wuidx;            // u-tile (16-wide) 0..23

  f32x4 acc[3][4];
#pragma unroll
  for (int g = 0; g < 3; g++)
#pragma unroll
    for (int i = 0; i < 4; i++)
#pragma unroll
      for (int r = 0; r < 4; r++) acc[g][i][r] = 0.0f;

  // A staging: thread -> row r0=tid>>2, k-chunk swizzled by (r0>>1)&3
  const int r0 = tid >> 2;
  const int kcg = ((tid & 3) ^ ((r0 >> 1) & 3)) * 8;
  const u16* Aptr  = A + (long)(mbase + r0) * K1 + kcg;
  const u16* Aptr2 = Aptr + 64 * K1;
  const u16* Bl = Bf + lane * 8;   // per-lane 16B within each 1KB fragment

  // A fragment read offsets within one LDS buffer
  int aoff[4];
#pragma unroll
  for (int i = 0; i < 4; i++) {
    int ra = wm + i * 16 + l16;
    aoff[i] = ra * 32 + ((quad ^ ((ra >> 1) & 3)) << 3);
  }

  // prologue: B(0) -> regs, then stage A(0), A(1) into buffers 0,1
  s16x8 bn[3];
#pragma unroll
  for (int g = 0; g < 3; g++)
    bn[g] = *(const s16x8*)(Bl + (long)((g * 24 + ut0) * 16 + 0) * 512);
  asm volatile("" ::: "memory");
  gld16(Aptr,       &As[0][tid * 8]);
  gld16(Aptr2,      &As[0][2048 + tid * 8]);
  gld16(Aptr + 32,  &As[1][tid * 8]);
  gld16(Aptr2 + 32, &As[1][2048 + tid * 8]);

#pragma unroll
  for (int t = 0; t < 16; ++t) {
    // current B = what we prefetched last iter
    s16x8 bcur[3];
#pragma unroll
    for (int g = 0; g < 3; g++) bcur[g] = bn[g];

    // prefetch next B (k-step t+1)
    if (t < 15) {
      const int tb = t + 1;
#pragma unroll
      for (int g = 0; g < 3; g++)
        bn[g] = *(const s16x8*)(Bl + (long)((g * 24 + ut0) * 16 + tb) * 512);
    }
    asm volatile("" ::: "memory");
    // stage A (k-step t+2), 2 ahead
    if (t < 14) {
      const int ta = t + 2;
      gld16(Aptr  + ta * 32, &As[(t + 2) & 3][tid * 8]);
      gld16(Aptr2 + ta * 32, &As[(t + 2) & 3][2048 + tid * 8]);
    }
    // counted wait: retire A(t) and B(t); leave newer prefetches in flight.
    // steady state outstanding after issue: A(t+1)2 B(t+1)3 A(t+2)2 = 7
    if (t < 14)       asm volatile("s_waitcnt vmcnt(7)" ::: "memory");
    else if (t == 14) asm volatile("s_waitcnt vmcnt(5)" ::: "memory");
    else              asm volatile("s_waitcnt vmcnt(0)" ::: "memory");
    __builtin_amdgcn_s_barrier();
    asm volatile("" ::: "memory");

    const u16* buf = &As[t & 3][0];
    s16x8 af[4];
#pragma unroll
    for (int i = 0; i < 4; i++) af[i] = *(const s16x8*)(buf + aoff[i]);

    __builtin_amdgcn_s_setprio(1);
#pragma unroll
    for (int g = 0; g < 3; g++) {
#pragma unroll
      for (int mi = 0; mi < 4; mi++) {
        acc[g][mi] = __builtin_amdgcn_mfma_f32_16x16x32_bf16(af[mi], bcur[g], acc[g][mi], 0, 0, 0);
      }
    }
    __builtin_amdgcn_s_setprio(0);
  }

  // epilogue: gates
  {
    int u = ucbase + wuidx * 16 + l16;
    float bz = bias[u] + bias[1152 + u];
    float br = bias[384 + u] + bias[1536 + u];
    float bh0 = bias[768 + u];
    float bh1 = bias[1920 + u];
#pragma unroll
    for (int mi = 0; mi < 4; mi++) {
#pragma unroll
      for (int rr = 0; rr < 4; rr++) {
        int row = mbase + wm + mi * 16 + quad * 4 + rr;
        float z  = sigmoidf_(acc[0][mi][rr] + bz);
        float rg = sigmoidf_(acc[1][mi][rr] + br);
        float hc = tanhf_(acc[2][mi][rr] + bh0 + rg * bh1);
        H1[(long)row * G1D + u] = f2bf((1.0f - z) * hc);
      }
    }
  }
}

// ---- FUSED GEMM2 + gates + FC + softmax ----
// R0-R5 version (empirically the fastest observed config; the R6 register-
// hoist + launch_bounds(256,2) variant cost ~+40us -- reverted).
__global__ __launch_bounds__(256) void gemm2fc(const u16* __restrict__ H1b,
                                               const u16* __restrict__ W2t,
                                               const float* __restrict__ bias2,
                                               const float* __restrict__ w1,
                                               const float* __restrict__ fb1,
                                               const float* __restrict__ w2,
                                               const float* __restrict__ fb2,
                                               const float* __restrict__ g1,
                                               const float* __restrict__ g2,
                                               float* __restrict__ out) {
  __shared__ u16 As[128 * 32];      // 8 KB
  __shared__ u16 Bs[48 * 32];       // 3 KB
  __shared__ float h2s[128 * 17];   // 8.5 KB
  const int tid = threadIdx.x;
  const int wave = tid >> 6, lane = tid & 63;
  const int quad = lane >> 4, l16 = lane & 15;
  const int mbase = blockIdx.x * 128;

  f32x4 acc[2][3];
#pragma unroll
  for (int i = 0; i < 2; i++)
#pragma unroll
    for (int j = 0; j < 3; j++)
#pragma unroll
      for (int r = 0; r < 4; r++) acc[i][j][r] = 0.0f;

  const int r0 = tid >> 2, kc = (tid & 3) * 8;
  const u16* Aptr = H1b + (long)(mbase + r0) * K2 + kc;

  for (int k0 = 0; k0 < K2; k0 += 32) {
    uint4 a0 = *(const uint4*)(Aptr + k0);
    uint4 a1 = *(const uint4*)(Aptr + 64 * K2 + k0);
    uint4 bv;
    if (tid < 192) bv = *(const uint4*)(W2t + r0 * K2 + k0 + kc);
    __syncthreads();
    *(uint4*)(&As[r0 * 32 + kc]) = a0;
    *(uint4*)(&As[(64 + r0) * 32 + kc]) = a1;
    if (tid < 192) *(uint4*)(&Bs[r0 * 32 + kc]) = bv;
    __syncthreads();
    s16x8 af[2], bfr[3];
#pragma unroll
    for (int mi = 0; mi < 2; mi++)
      af[mi] = *(const s16x8*)(&As[(wave * 32 + mi * 16 + l16) * 32 + quad * 8]);
#pragma unroll
    for (int ni = 0; ni < 3; ni++)
      bfr[ni] = *(const s16x8*)(&Bs[(ni * 16 + l16) * 32 + quad * 8]);
#pragma unroll
    for (int mi = 0; mi < 2; mi++)
#pragma unroll
      for (int ni = 0; ni < 3; ni++)
        acc[mi][ni] = __builtin_amdgcn_mfma_f32_16x16x32_bf16(af[mi], bfr[ni], acc[mi][ni], 0, 0, 0);
  }

  {
    const int u = l16;
    const float b0z = bias2[u],      b1z = bias2[48 + u];
    const float b0r = bias2[16 + u], b1r = bias2[64 + u];
    const float b0h = bias2[32 + u], b1h = bias2[80 + u];
#pragma unroll
    for (int mi = 0; mi < 2; mi++) {
#pragma unroll
      for (int rr = 0; rr < 4; rr++) {
        int row_l = wave * 32 + mi * 16 + quad * 4 + rr;
        float z  = sigmoidf_(acc[mi][0][rr] + b0z + b1z);
        float rg = sigmoidf_(acc[mi][1][rr] + b0r + b1r);
        float hc = tanhf_(acc[mi][2][rr] + b0h + rg * b1h);
        h2s[row_l * 17 + u] = (1.0f - z) * hc;
      }
    }
  }
  __syncthreads();

  // Phase 2: fc + softmax, wave-per-row (32 rows per wave)
#pragma unroll 1
  for (int r = 0; r < 32; r++) {
    int row_l = wave * 32 + r;
    float h[16];
#pragma unroll
    for (int uu = 0; uu < 16; uu++) h[uu] = h2s[row_l * 17 + uu];
    float e[4];
    float mx = -1e30f;
#pragma unroll
    for (int i = 0; i < 4; i++) {
      int c = i * 64 + lane;
      float a1 = fb1[c], a2 = fb2[c];
#pragma unroll
      for (int uu = 0; uu < 16; uu++) {
        a1 = fmaf(h[uu], w1[uu * 256 + c], a1);
        a2 = fmaf(h[uu], w2[uu * 256 + c], a2);
      }
      float d = g1[c] * tanhf_(a1) + g2[c] * tanhf_(a2);
      e[i] = d;
      mx = fmaxf(mx, d);
    }
#pragma unroll
    for (int off = 32; off >= 1; off >>= 1) mx = fmaxf(mx, __shfl_xor(mx, off, 64));
    float sum = 0.0f;
#pragma unroll
    for (int i = 0; i < 4; i++) { e[i] = __expf(e[i] - mx); sum += e[i]; }
#pragma unroll
    for (int off = 32; off >= 1; off >>= 1) sum += __shfl_xor(sum, off, 64);
    float inv = 1.0f / sum;
    float* orow = out + (long)(mbase + row_l) * NL;
#pragma unroll
    for (int i = 0; i < 4; i++) orow[i * 64 + lane] = e[i] * inv;
  }
}

extern "C" void kernel_launch(void* const* d_in, const int* in_sizes, int n_in,
                              void* d_out, int out_size, void* d_ws, size_t ws_size,
                              hipStream_t stream) {
  const float* x1   = (const float*)d_in[0];
  const float* x2   = (const float*)d_in[1];
  const float* w1k  = (const float*)d_in[2];   // gru1_kernel (512 x 1152)
  const float* b1g  = (const float*)d_in[4];   // gru1_bias (2 x 1152)
  const float* w2k  = (const float*)d_in[5];   // gru2_kernel (384 x 48)
  const float* b2g  = (const float*)d_in[7];   // gru2_bias (2 x 48)
  const float* fcw1 = (const float*)d_in[8];
  const float* fcb1 = (const float*)d_in[9];
  const float* fcw2 = (const float*)d_in[10];
  const float* fcb2 = (const float*)d_in[11];
  const float* fcg1 = (const float*)d_in[12];
  const float* fcg2 = (const float*)d_in[13];
  float* out = (float*)d_out;

  char* ws = (char*)d_ws;
  u16* Abf = (u16*)(ws + 0);            // 65536*512*2   = 67108864
  u16* W1t = (u16*)(ws + 67108864);     // 1152*512*2    = 1179648 (16x16 frag-major)
  u16* H1  = (u16*)(ws + 68288512);     // 65536*384*2   = 50331648
  u16* W2t = (u16*)(ws + 118620160);    // 48*384*2      = 36864

  hipLaunchKernelGGL(prep_all, dim3(16576), dim3(256), 0, stream,
                     x1, x2, Abf, w1k, W1t, w2k, W2t);
  hipLaunchKernelGGL(gemm1gate, dim3(6144), dim3(256), 0, stream, Abf, W1t, b1g, H1);
  hipLaunchKernelGGL(gemm2fc, dim3(512), dim3(256), 0, stream, H1, W2t, b2g,
                     fcw1, fcb1, fcw2, fcb2, fcg1, fcg2, out);
}